// Round 7
// baseline (358.323 us; speedup 1.0000x reference)
//
#include <hip/hip_runtime.h>
#include <math.h>

// NeuralMemory on MI355X — R7: B-resident tall GEMMs + coalesced LDS-staged
// epilogue + full A-prefetch.
//  - All 16 A frag loads issue BEFORE the B LDS fill: barrier drain hides them.
//  - K-loop is pure LDS->MFMA (no vmcnt stalls).
//  - Epilogue: acc staged to LDS (fp32, 128x132 pad), then row-major coalesced
//    uint4/float4 epilogue; column-sum (bias grads) reduced from LDS.

#define NTOK 32768
#define NM ((size_t)NTOK * 256)
#define LRc 1e-3f
#define WDc 1e-2f
#define EPSc 1e-8f

typedef __attribute__((ext_vector_type(8))) short bf16x8;
typedef __attribute__((ext_vector_type(4))) float f32x4;

__device__ __forceinline__ float b2f(unsigned short u) {
    union { unsigned int i; float f; } c;
    c.i = ((unsigned int)u) << 16;
    return c.f;
}
__device__ __forceinline__ unsigned short f2b(float f) {
    union { float f; unsigned int i; } c;
    c.f = f;
    unsigned int i = c.i;
    return (unsigned short)((i + 0x7FFFu + ((i >> 16) & 1u)) >> 16);
}
__device__ __forceinline__ float sigm(float z) { return 1.f / (1.f + __expf(-z)); }
__device__ __forceinline__ float siluf(float z) { return z * sigm(z); }
__device__ __forceinline__ float dsiluf(float z) {
    float s = sigm(z);
    return s * (1.f + z * (1.f - s));
}
__device__ __forceinline__ uint4 pack8(const float* f) {
    uint4 o;
    o.x = (unsigned)f2b(f[0]) | ((unsigned)f2b(f[1]) << 16);
    o.y = (unsigned)f2b(f[2]) | ((unsigned)f2b(f[3]) << 16);
    o.z = (unsigned)f2b(f[4]) | ((unsigned)f2b(f[5]) << 16);
    o.w = (unsigned)f2b(f[6]) | ((unsigned)f2b(f[7]) << 16);
    return o;
}
__device__ __forceinline__ void unpack8(uint4 u, float* f) {
    f[0] = b2f(u.x & 0xFFFF); f[1] = b2f(u.x >> 16);
    f[2] = b2f(u.y & 0xFFFF); f[3] = b2f(u.y >> 16);
    f[4] = b2f(u.z & 0xFFFF); f[5] = b2f(u.z >> 16);
    f[6] = b2f(u.w & 0xFFFF); f[7] = b2f(u.w >> 16);
}

#define BSTRIDE 264  // bf16 B tile row stride (256+8)
#define CSTRIDE 132  // fp32 C staging row stride (128+4)

// ---------------------------------------------------------------------------
// B-resident tall GEMM: C[M,256] = A[M,256] @ B, Bt[n][k] = B[k][n].
// Grid (2, M/128 [, z]); block 512 thr = 8 waves = 4 m-stripes x 2 n-halves.
// EPI 0: Cb = A@B (batched z)                                  projections
// EPI 1: z=acc+bias; Zout=z; Cb = A+silu(z)                    fwd layer 0
// EPI 5: z=acc+bias; h2=A+silu(z); dh=alr*(2/D)*(h2-V);        fwd layer 1 +
//        dz=dh*dsilu(z); Cb=dz; Rout=dh; gb += colsum(dz)       bwd elemwise
// EPI 2: dh1=acc+Rin; dz0=dh1*dsilu(Zin); Cb=dz0; gb+=colsum   bwd layer 0
// EPI 3: Cb = A + silu(acc+bias)                               retrieved L0
// EPI 4: Cf = A + silu(acc+bias)  (fp32 out)                   retrieved L1
// ---------------------------------------------------------------------------
template <int EPI>
__global__ __launch_bounds__(512, 4) void wgemm_k(
    const unsigned short* __restrict__ A, const unsigned short* __restrict__ Bt,
    const float* __restrict__ bias, const unsigned short* __restrict__ Rin,
    const unsigned short* __restrict__ Zin, const unsigned short* __restrict__ Vb,
    const float* __restrict__ alr, unsigned short* __restrict__ Cb,
    float* __restrict__ Cf, unsigned short* __restrict__ Zout,
    unsigned short* __restrict__ Rout, float* __restrict__ gb, size_t zcs) {
    __shared__ __align__(16) unsigned char smem[128 * BSTRIDE * 2];  // 67584 B
    unsigned short* Bs = (unsigned short*)smem;
    float* Cs = (float*)smem;

    Bt += (size_t)blockIdx.z * 65536;
    Cb += (size_t)blockIdx.z * zcs;
    const int n0 = blockIdx.x * 128, m0 = blockIdx.y * 128;
    const int tid = threadIdx.x, lane = tid & 63, wave = tid >> 6;
    const int ms = wave >> 1, nh = wave & 1;
    const int wm0 = m0 + ms * 32, lnb = nh * 64;
    const int fr = lane & 15, fk = (lane >> 4) * 8;

    // ---- issue ALL A-frag loads first (latency hidden behind B fill+barrier)
    const size_t base_a = (size_t)(wm0 + fr) * 256 + fk;
    bf16x8 ap[8][2];
#pragma unroll
    for (int p = 0; p < 8; p++) {
        ap[p][0] = *(const bf16x8*)(A + base_a + p * 32);
        ap[p][1] = *(const bf16x8*)(A + base_a + 4096 + p * 32);
    }

    // ---- fill B tile (128 rows x 256 shorts) into LDS
#pragma unroll
    for (int it = 0; it < 8; it++) {
        int idx = it * 512 + tid;
        int row = idx >> 5, c8 = (idx & 31) * 8;
        *(uint4*)&Bs[row * BSTRIDE + c8] =
            *(const uint4*)(Bt + (size_t)(n0 + row) * 256 + c8);
    }
    __syncthreads();

    f32x4 acc[2][4];
#pragma unroll
    for (int s = 0; s < 2; s++)
#pragma unroll
        for (int t = 0; t < 4; t++) acc[s][t] = (f32x4){0.f, 0.f, 0.f, 0.f};

#pragma unroll
    for (int it = 0; it < 8; it++) {
        const int k0 = it * 32;
        bf16x8 bfr[4];
#pragma unroll
        for (int t = 0; t < 4; t++)
            bfr[t] = *(const bf16x8*)&Bs[(lnb + t * 16 + fr) * BSTRIDE + k0 + fk];
#pragma unroll
        for (int t = 0; t < 4; t++) {
            acc[0][t] = __builtin_amdgcn_mfma_f32_16x16x32_bf16(ap[it][0], bfr[t],
                                                                acc[0][t], 0, 0, 0);
            acc[1][t] = __builtin_amdgcn_mfma_f32_16x16x32_bf16(ap[it][1], bfr[t],
                                                                acc[1][t], 0, 0, 0);
        }
    }
    __syncthreads();  // all waves done reading B

    // ---- stage acc into LDS (fp32) in C/D layout
    const int r0 = (lane >> 4) * 4, cc = lane & 15;
#pragma unroll
    for (int s = 0; s < 2; s++)
#pragma unroll
        for (int t = 0; t < 4; t++) {
            f32x4 c = acc[s][t];
#pragma unroll
            for (int r = 0; r < 4; r++)
                Cs[(ms * 32 + s * 16 + r0 + r) * CSTRIDE + lnb + t * 16 + cc] =
                    c[r];
        }
    __syncthreads();

    // ---- coalesced row-major epilogue: thread = 1 row x 32 cols
    const int row = tid >> 2, c0l = (tid & 3) * 32;
    const int grow = m0 + row;
    float lalr = 0.f;
    if (EPI == 5) lalr = alr[grow] * (2.f / 256.f);
#pragma unroll
    for (int ch = 0; ch < 4; ch++) {
        const int cl = c0l + ch * 8;
        const int gcol = n0 + cl;
        const size_t off = (size_t)grow * 256 + gcol;
        float v[8];
        *(float4*)&v[0] = *(const float4*)&Cs[row * CSTRIDE + cl];
        *(float4*)&v[4] = *(const float4*)&Cs[row * CSTRIDE + cl + 4];
        if (EPI == 0) {
            *(uint4*)(Cb + off) = pack8(v);
        } else if (EPI == 1) {
            float bv[8], a[8], z[8], o[8];
            *(float4*)&bv[0] = *(const float4*)(bias + gcol);
            *(float4*)&bv[4] = *(const float4*)(bias + gcol + 4);
            unpack8(*(const uint4*)(A + off), a);
#pragma unroll
            for (int j = 0; j < 8; j++) {
                z[j] = v[j] + bv[j];
                o[j] = a[j] + siluf(z[j]);
            }
            *(uint4*)(Zout + off) = pack8(z);
            *(uint4*)(Cb + off) = pack8(o);
        } else if (EPI == 5) {
            float bv[8], a[8], vv[8], dz[8], dh[8];
            *(float4*)&bv[0] = *(const float4*)(bias + gcol);
            *(float4*)&bv[4] = *(const float4*)(bias + gcol + 4);
            unpack8(*(const uint4*)(A + off), a);
            unpack8(*(const uint4*)(Vb + off), vv);
#pragma unroll
            for (int j = 0; j < 8; j++) {
                float z = v[j] + bv[j];
                float h2 = a[j] + siluf(z);
                dh[j] = lalr * (h2 - vv[j]);
                dz[j] = dh[j] * dsiluf(z);
            }
            *(uint4*)(Cb + off) = pack8(dz);
            *(uint4*)(Rout + off) = pack8(dh);
            *(float4*)&Cs[row * CSTRIDE + cl] = *(float4*)&dz[0];
            *(float4*)&Cs[row * CSTRIDE + cl + 4] = *(float4*)&dz[4];
        } else if (EPI == 2) {
            float ri[8], zi[8], dz0[8];
            unpack8(*(const uint4*)(Rin + off), ri);
            unpack8(*(const uint4*)(Zin + off), zi);
#pragma unroll
            for (int j = 0; j < 8; j++) {
                float dh1 = v[j] + ri[j];
                dz0[j] = dh1 * dsiluf(zi[j]);
            }
            *(uint4*)(Cb + off) = pack8(dz0);
            *(float4*)&Cs[row * CSTRIDE + cl] = *(float4*)&dz0[0];
            *(float4*)&Cs[row * CSTRIDE + cl + 4] = *(float4*)&dz0[4];
        } else if (EPI == 3) {
            float bv[8], a[8], o[8];
            *(float4*)&bv[0] = *(const float4*)(bias + gcol);
            *(float4*)&bv[4] = *(const float4*)(bias + gcol + 4);
            unpack8(*(const uint4*)(A + off), a);
#pragma unroll
            for (int j = 0; j < 8; j++) o[j] = a[j] + siluf(v[j] + bv[j]);
            *(uint4*)(Cb + off) = pack8(o);
        } else {  // EPI 4: fp32 final
            float bv[8], a[8];
            *(float4*)&bv[0] = *(const float4*)(bias + gcol);
            *(float4*)&bv[4] = *(const float4*)(bias + gcol + 4);
            unpack8(*(const uint4*)(A + off), a);
            float o[8];
#pragma unroll
            for (int j = 0; j < 8; j++) o[j] = a[j] + siluf(v[j] + bv[j]);
            *(float4*)(Cf + off) = *(float4*)&o[0];
            *(float4*)(Cf + off + 4) = *(float4*)&o[4];
        }
    }

    // ---- fused column sums (bias grads) from LDS
    if (EPI == 5 || EPI == 2) {
        __syncthreads();
        const int col = tid & 127, q = tid >> 7;
        float s = 0.f;
#pragma unroll
        for (int r = 0; r < 32; r++) s += Cs[(q * 32 + r) * CSTRIDE + col];
        atomicAdd(&gb[n0 + col], s);
    }
}

// ---------------------------------------------------------------------------
// Reduction GEMM with transpose-on-load: gW[l][i][j] = sum_t X[t][i] dz[t][j]
// from row-major X, dz. Grid (2,2,128): j0, i0, z (layer=z>>6, chunk=z&63 of
// 512 tokens). LDS tiles 128x32 with row stride 40 shorts. fp32 partials.
// ---------------------------------------------------------------------------
__global__ __launch_bounds__(256, 2) void rgemm_k(
    const unsigned short* __restrict__ Kb, const unsigned short* __restrict__ h1b,
    const unsigned short* __restrict__ dz0b,
    const unsigned short* __restrict__ dz1b, float* __restrict__ pbuf) {
    __shared__ unsigned short As[128 * 40];
    __shared__ unsigned short Bs2[128 * 40];
    const int z = blockIdx.z, layer = z >> 6, zc = z & 63;
    const unsigned short* Ag = layer ? h1b : Kb;
    const unsigned short* Bg = layer ? dz1b : dz0b;
    const int t0 = zc * 512;
    const int j0 = blockIdx.x * 128, i0 = blockIdx.y * 128;
    const int tid = threadIdx.x, lane = tid & 63, wave = tid >> 6;
    const int wr = (wave >> 1) * 64, wc = (wave & 1) * 64;
    const int fr = lane & 15, fk = (lane >> 4) * 8;
    const int pt = (tid >> 4) * 2, pi = (tid & 15) * 8;

    f32x4 acc[4][4];
#pragma unroll
    for (int i = 0; i < 4; i++)
#pragma unroll
        for (int j = 0; j < 4; j++) acc[i][j] = (f32x4){0.f, 0.f, 0.f, 0.f};

    for (int tt = t0; tt < t0 + 512; tt += 32) {
        uint4 a0 = *(const uint4*)(Ag + (size_t)(tt + pt) * 256 + i0 + pi);
        uint4 a1 = *(const uint4*)(Ag + (size_t)(tt + pt + 1) * 256 + i0 + pi);
        uint4 b0 = *(const uint4*)(Bg + (size_t)(tt + pt) * 256 + j0 + pi);
        uint4 b1 = *(const uint4*)(Bg + (size_t)(tt + pt + 1) * 256 + j0 + pi);
        const unsigned int* aw0 = (const unsigned int*)&a0;
        const unsigned int* aw1 = (const unsigned int*)&a1;
        const unsigned int* bw0 = (const unsigned int*)&b0;
        const unsigned int* bw1 = (const unsigned int*)&b1;
#pragma unroll
        for (int ii = 0; ii < 8; ii++) {
            unsigned int alo = (aw0[ii >> 1] >> (16 * (ii & 1))) & 0xFFFFu;
            unsigned int ahi = (aw1[ii >> 1] >> (16 * (ii & 1))) & 0xFFFFu;
            unsigned int blo = (bw0[ii >> 1] >> (16 * (ii & 1))) & 0xFFFFu;
            unsigned int bhi = (bw1[ii >> 1] >> (16 * (ii & 1))) & 0xFFFFu;
            const int ad = ((pi + ii) * 40 + pt) >> 1;
            ((unsigned int*)As)[ad] = alo | (ahi << 16);
            ((unsigned int*)Bs2)[ad] = blo | (bhi << 16);
        }
        __syncthreads();
        bf16x8 af[4], bfr[4];
#pragma unroll
        for (int i = 0; i < 4; i++) {
            af[i] = *(const bf16x8*)&As[(wr + i * 16 + fr) * 40 + fk];
            bfr[i] = *(const bf16x8*)&Bs2[(wc + i * 16 + fr) * 40 + fk];
        }
#pragma unroll
        for (int i = 0; i < 4; i++)
#pragma unroll
            for (int j = 0; j < 4; j++)
                acc[i][j] = __builtin_amdgcn_mfma_f32_16x16x32_bf16(
                    af[i], bfr[j], acc[i][j], 0, 0, 0);
        __syncthreads();
    }

    float* P = pbuf + (size_t)((layer << 6) + zc) * 65536;
    const int r0 = (lane >> 4) * 4, cc = lane & 15;
#pragma unroll
    for (int mi = 0; mi < 4; mi++)
#pragma unroll
        for (int ni = 0; ni < 4; ni++) {
            f32x4 c = acc[mi][ni];
#pragma unroll
            for (int r = 0; r < 4; r++)
                P[(size_t)(i0 + wr + mi * 16 + r0 + r) * 256 +
                  (j0 + wc + ni * 16 + cc)] = c[r];
        }
}

__global__ void reduce_k(const float* __restrict__ pbuf, float* __restrict__ accW) {
    int idx = blockIdx.x * 256 + threadIdx.x;  // 131072
    int layer = idx >> 16, rc = idx & 65535;
    const float* p = pbuf + (size_t)layer * 64 * 65536 + rc;
    float s = 0.f;
#pragma unroll 8
    for (int c = 0; c < 64; c++) s += p[(size_t)c * 65536];
    accW[idx] = s;
}

// x fp32 -> xb bf16 + alr = 0.1*sigmoid(x@Wlr+blr), one wave per row
__global__ __launch_bounds__(256) void prep_k(const float* __restrict__ x,
                                              const float* __restrict__ Wlr,
                                              const float* __restrict__ blr,
                                              unsigned short* __restrict__ xb,
                                              float* __restrict__ alr) {
    const int wave = threadIdx.x >> 6, lane = threadIdx.x & 63;
    const int r = blockIdx.x * 4 + wave;
    float4 w = *(const float4*)(Wlr + lane * 4);
    float4 v = *(const float4*)(x + (size_t)r * 256 + lane * 4);
    float s = v.x * w.x + v.y * w.y + v.z * w.z + v.w * w.w;
    unsigned int p0 = (unsigned int)f2b(v.x) | ((unsigned int)f2b(v.y) << 16);
    unsigned int p1 = (unsigned int)f2b(v.z) | ((unsigned int)f2b(v.w) << 16);
    *(uint2*)(xb + (size_t)r * 256 + lane * 4) = make_uint2(p0, p1);
#pragma unroll
    for (int off = 32; off; off >>= 1) s += __shfl_down(s, off);
    if (lane == 0) alr[r] = 0.1f * sigm(s + blr[0]);
}

// weight prep: z=0..4 transpose+cvt {Wk,Wq,Wv,Ws0,Ws1}; z=5 straight cvt Ws1
__global__ void wprep_k(const float* __restrict__ Wk, const float* __restrict__ Wq,
                        const float* __restrict__ Wv, const float* __restrict__ Ws,
                        unsigned short* __restrict__ wt) {
    const int z = blockIdx.y;
    const int idx = blockIdx.x * 256 + threadIdx.x;  // 0..65535
    const float* src = z == 0 ? Wk : z == 1 ? Wq : z == 2 ? Wv
                     : z == 3 ? Ws : Ws + 65536;
    unsigned short* dst = wt + (size_t)z * 65536;
    float v = src[idx];
    if (z == 5)
        dst[idx] = f2b(v);
    else
        dst[(idx & 255) * 256 + (idx >> 8)] = f2b(v);
}

__global__ void adamw_w_k(const float* __restrict__ Ws,
                          const float* __restrict__ accW,
                          unsigned short* __restrict__ nWt,
                          float* __restrict__ outSW) {
    int idx = blockIdx.x * 256 + threadIdx.x;  // 131072
    float g = accW[idx];
    outSW[idx] = -g;
    float nw = Ws[idx] * (1.f - LRc * WDc) - LRc * g / (fabsf(g) + EPSc);
    int l = idx >> 16, k = (idx >> 8) & 255, n = idx & 255;
    nWt[(size_t)l * 65536 + n * 256 + k] = f2b(nw);
}

__global__ void adamw_b_k(const float* __restrict__ bs,
                          const float* __restrict__ accB,
                          float* __restrict__ nb, float* __restrict__ outSb) {
    int idx = blockIdx.x * 256 + threadIdx.x;  // 512
    float g = accB[idx];
    outSb[idx] = -g;
    nb[idx] = bs[idx] * (1.f - LRc * WDc) - LRc * g / (fabsf(g) + EPSc);
}

__global__ void zero_k(float* p, int n) {
    int i = blockIdx.x * 256 + threadIdx.x;
    if (i < n) p[i] = 0.f;
}

extern "C" void kernel_launch(void* const* d_in, const int* in_sizes, int n_in,
                              void* d_out, int out_size, void* d_ws,
                              size_t ws_size, hipStream_t stream) {
    const float* x = (const float*)d_in[0];
    const float* Wk = (const float*)d_in[1];
    const float* Wq = (const float*)d_in[2];
    const float* Wv = (const float*)d_in[3];
    const float* Wlr = (const float*)d_in[4];
    const float* blr = (const float*)d_in[5];
    const float* Ws = (const float*)d_in[6];
    const float* bs = (const float*)d_in[7];

    unsigned short* S = (unsigned short*)d_ws;
    unsigned short* xb = S + 0 * NM;  // dead after proj; reused as r1b
    unsigned short* Kb = S + 1 * NM;
    unsigned short* Qb = S + 2 * NM;
    unsigned short* Vb = S + 3 * NM;
    unsigned short* z0b = S + 4 * NM;
    unsigned short* h1b = S + 5 * NM;
    unsigned short* dz1b = S + 6 * NM;
    unsigned short* dh2b = S + 7 * NM;
    unsigned short* dz0b = S + 8 * NM;
    float* pbuf = (float*)(S + 9 * NM);  // 32 MB (slots 9-10)
    unsigned short* r1b = xb;

    unsigned short* wt = S + 11 * NM;
    unsigned short* W0t = wt + 3 * 65536;
    unsigned short* W1t = wt + 4 * 65536;
    unsigned short* W1b = wt + 5 * 65536;
    unsigned short* nW0t = wt + 6 * 65536;
    unsigned short* nW1t = wt + 7 * 65536;
    float* ft = (float*)(wt + 8 * 65536);
    float* alr = ft;              // 32768
    float* accW = ft + 32768;     // 131072
    float* accB = accW + 131072;  // 512
    float* nb = accB + 512;       // 512

    float* out_ret = (float*)d_out;
    float* out_sW = out_ret + NM;
    float* out_sb = out_sW + 131072;

    dim3 blk5(512);
    dim3 blk(256);
    dim3 g_tall(2, 256);

    zero_k<<<2, blk, 0, stream>>>(accB, 512);
    prep_k<<<8192, blk, 0, stream>>>(x, Wlr, blr, xb, alr);
    wprep_k<<<dim3(256, 6), blk, 0, stream>>>(Wk, Wq, Wv, Ws, wt);

    // projections K,Q,V (batched over z)
    wgemm_k<0><<<dim3(2, 256, 3), blk5, 0, stream>>>(
        xb, wt, nullptr, nullptr, nullptr, nullptr, nullptr, Kb, nullptr,
        nullptr, nullptr, nullptr, NM);

    // fwd layer 0: h1 = K + silu(K@W0 + b0); saves z0
    wgemm_k<1><<<g_tall, blk5, 0, stream>>>(Kb, W0t, bs, nullptr, nullptr,
                                            nullptr, nullptr, h1b, nullptr,
                                            z0b, nullptr, nullptr, 0);

    // fwd layer 1 + bwd elementwise (+ gb1 colsum fused)
    wgemm_k<5><<<g_tall, blk5, 0, stream>>>(h1b, W1t, bs + 256, nullptr,
                                            nullptr, Vb, alr, dz1b, nullptr,
                                            nullptr, dh2b, accB + 256, 0);

    // bwd layer 0: dz0 = (dz1@W1^T + dh2) * dsilu(z0) (+ gb0 colsum fused)
    wgemm_k<2><<<g_tall, blk5, 0, stream>>>(dz1b, W1b, nullptr, dh2b, z0b,
                                            nullptr, nullptr, dz0b, nullptr,
                                            nullptr, nullptr, accB, 0);

    // weight grads: transpose-on-load split-K partials + reduce
    rgemm_k<<<dim3(2, 2, 128), blk, 0, stream>>>(Kb, h1b, dz0b, dz1b, pbuf);
    reduce_k<<<512, blk, 0, stream>>>(pbuf, accW);

    // AdamW + surprises
    adamw_w_k<<<512, blk, 0, stream>>>(Ws, accW, nW0t, out_sW);
    adamw_b_k<<<2, blk, 0, stream>>>(bs, accB, nb, out_sb);

    // retrieved with new weights (two tall passes)
    wgemm_k<3><<<g_tall, blk5, 0, stream>>>(Qb, nW0t, nb, nullptr, nullptr,
                                            nullptr, nullptr, r1b, nullptr,
                                            nullptr, nullptr, nullptr, 0);
    wgemm_k<4><<<g_tall, blk5, 0, stream>>>(r1b, nW1t, nb + 256, nullptr,
                                            nullptr, nullptr, nullptr, nullptr,
                                            out_ret, nullptr, nullptr, nullptr,
                                            0);
}

// Round 8
// 288.334 us; speedup vs baseline: 1.2427x; 1.2427x over previous
//
#include <hip/hip_runtime.h>
#include <math.h>

// NeuralMemory on MI355X — R8: operand-swapped streaming GEMM.
// MFMA A-slot = W-frags (LDS-resident half-tile, padded stride 264 shorts);
// MFMA B-slot = X-frags: per 16-token wave-job just 8 bf16x8 (32 VGPR), all 8
// global_load_dwordx4 issued off ONE base pointer with imm offsets -> compiler
// keeps 8 KB/wave in flight. Output lands (token=lane&15, 4 contiguous cols
// per lane); wave-private LDS repack => 64B-segment coalesced stores.

#define NTOK 32768
#define NM ((size_t)NTOK * 256)
#define LRc 1e-3f
#define WDc 1e-2f
#define EPSc 1e-8f

typedef __attribute__((ext_vector_type(8))) short bf16x8;
typedef __attribute__((ext_vector_type(4))) float f32x4;

__device__ __forceinline__ float b2f(unsigned short u) {
    union { unsigned int i; float f; } c;
    c.i = ((unsigned int)u) << 16;
    return c.f;
}
__device__ __forceinline__ unsigned short f2b(float f) {
    union { float f; unsigned int i; } c;
    c.f = f;
    unsigned int i = c.i;
    return (unsigned short)((i + 0x7FFFu + ((i >> 16) & 1u)) >> 16);
}
__device__ __forceinline__ float sigm(float z) { return 1.f / (1.f + __expf(-z)); }
__device__ __forceinline__ float siluf(float z) { return z * sigm(z); }
__device__ __forceinline__ float dsiluf(float z) {
    float s = sigm(z);
    return s * (1.f + z * (1.f - s));
}
__device__ __forceinline__ void unpack4(uint2 u, float* f) {
    f[0] = b2f(u.x & 0xFFFF); f[1] = b2f(u.x >> 16);
    f[2] = b2f(u.y & 0xFFFF); f[3] = b2f(u.y >> 16);
}
__device__ __forceinline__ uint2 pack4(const float* f) {
    uint2 o;
    o.x = (unsigned)f2b(f[0]) | ((unsigned)f2b(f[1]) << 16);
    o.y = (unsigned)f2b(f[2]) | ((unsigned)f2b(f[3]) << 16);
    return o;
}

#define WSTR 264   // W tile row stride in shorts (33x 16B units, odd => rotate)
#define SSTR 40    // scratch row stride in shorts (80 B, 16B-aligned)

// ---------------------------------------------------------------------------
// Operand-swapped tall GEMM: C[M,256] = X[M,256] @ B with Bt[n][k]=B[k][n].
// Grid (2 n-halves, M/128 [, z]); block 512 thr = 8 waves; wave = 16 tokens
// x 128 ncols (8 MFMA col-tiles). W half-tile in LDS.
// EPI 0: Cb = X@B (batched z)                         projections
// EPI 1: z=acc+bias; Zout=z; Cb = X+silu(z)           fwd layer 0
// EPI 5: z=acc+bias; h2=X+silu(z); dh=alr'* (h2-V);   fwd layer 1 + bwd elem
//        dz=dh*dsilu(z); Cb=dz; Rout=dh
// EPI 2: dz0=(acc+Rin)*dsilu(Zin); Cb=dz0             bwd layer 0
// EPI 3: Cb = X + silu(acc+bias)                      retrieved L0
// EPI 4: Cf = X + silu(acc+bias)  (fp32 out)          retrieved L1
// ---------------------------------------------------------------------------
template <int EPI>
__global__ __launch_bounds__(512, 4) void wgemm_k(
    const unsigned short* __restrict__ A, const unsigned short* __restrict__ Bt,
    const float* __restrict__ bias, const unsigned short* __restrict__ Rin,
    const unsigned short* __restrict__ Zin, const unsigned short* __restrict__ Vb,
    const float* __restrict__ alr, unsigned short* __restrict__ Cb,
    float* __restrict__ Cf, unsigned short* __restrict__ Zout,
    unsigned short* __restrict__ Rout, size_t zcs) {
    __shared__ unsigned short Ws[128 * WSTR];
    __shared__ unsigned short Sc[8][16 * SSTR];
    Bt += (size_t)blockIdx.z * 65536;
    Cb += (size_t)blockIdx.z * zcs;
    const int n0 = blockIdx.x * 128, m0 = blockIdx.y * 128;
    const int tid = threadIdx.x, lane = tid & 63, wv = tid >> 6;
    const int cc = lane & 15, q = lane >> 4;

    // ---- X-frag loads: 8 instrs off one base (imm offsets), 8 KB/wave in flight
    const int t0 = m0 + wv * 16;
    const unsigned short* xp = A + (size_t)(t0 + cc) * 256 + q * 8;
    bf16x8 xf[8];
#pragma unroll
    for (int c = 0; c < 8; c++) xf[c] = *(const bf16x8*)(xp + c * 32);

    // ---- W half-tile fill: [128 n-rows][256 k] shorts, padded stride
#pragma unroll
    for (int it = 0; it < 8; it++) {
        int i = it * 512 + tid;
        int row = i >> 5, g8 = i & 31;
        *(uint4*)&Ws[row * WSTR + g8 * 8] =
            *(const uint4*)(Bt + (size_t)(n0 + row) * 256 + g8 * 8);
    }
    __syncthreads();

    f32x4 acc[8];
#pragma unroll
    for (int t = 0; t < 8; t++) acc[t] = (f32x4){0.f, 0.f, 0.f, 0.f};

#pragma unroll
    for (int c = 0; c < 8; c++) {
#pragma unroll
        for (int nt = 0; nt < 8; nt++) {
            bf16x8 wf = *(const bf16x8*)&Ws[(nt * 16 + cc) * WSTR + c * 32 + q * 8];
            acc[nt] = __builtin_amdgcn_mfma_f32_16x16x32_bf16(wf, xf[c],
                                                              acc[nt], 0, 0, 0);
        }
    }

    // ---- epilogue: lane holds token t0+cc, cols nt*16 + 4q + r (r=0..3)
    const int tok = t0 + cc;
    float lalr = 0.f;
    if (EPI == 5) lalr = alr[tok] * (2.f / 256.f);
    unsigned short* sc = &Sc[wv][0];
    const int rtok = lane >> 2, roct = (lane & 3) * 8;  // repack read indices

#pragma unroll
    for (int pr = 0; pr < 4; pr++) {  // tile pairs (2pr, 2pr+1) = 32 cols
        float o2[2][4], z2[2][4];     // primary / secondary quad outputs
#pragma unroll
        for (int h = 0; h < 2; h++) {
            const int nt = pr * 2 + h;
            const int gcol = n0 + nt * 16 + q * 4;
            const size_t off = (size_t)tok * 256 + gcol;
            f32x4 c = acc[nt];
            float v[4] = {c[0], c[1], c[2], c[3]};
            if (EPI == 0) {
#pragma unroll
                for (int r = 0; r < 4; r++) o2[h][r] = v[r];
            } else if (EPI == 1) {
                float bv[4], a[4];
                *(float4*)bv = *(const float4*)(bias + gcol);
                unpack4(*(const uint2*)(A + off), a);
#pragma unroll
                for (int r = 0; r < 4; r++) {
                    float z = v[r] + bv[r];
                    z2[h][r] = z;
                    o2[h][r] = a[r] + siluf(z);
                }
            } else if (EPI == 5) {
                float bv[4], a[4], vv[4];
                *(float4*)bv = *(const float4*)(bias + gcol);
                unpack4(*(const uint2*)(A + off), a);
                unpack4(*(const uint2*)(Vb + off), vv);
#pragma unroll
                for (int r = 0; r < 4; r++) {
                    float z = v[r] + bv[r];
                    float h2 = a[r] + siluf(z);
                    float dh = lalr * (h2 - vv[r]);
                    o2[h][r] = dh * dsiluf(z);  // dz
                    z2[h][r] = dh;              // dh
                }
            } else if (EPI == 2) {
                float ri[4], zi[4];
                unpack4(*(const uint2*)(Rin + off), ri);
                unpack4(*(const uint2*)(Zin + off), zi);
#pragma unroll
                for (int r = 0; r < 4; r++)
                    o2[h][r] = (v[r] + ri[r]) * dsiluf(zi[r]);
            } else {  // EPI 3 / 4
                float bv[4], a[4];
                *(float4*)bv = *(const float4*)(bias + gcol);
                unpack4(*(const uint2*)(A + off), a);
#pragma unroll
                for (int r = 0; r < 4; r++) o2[h][r] = a[r] + siluf(v[r] + bv[r]);
            }
            if (EPI == 4) {  // fp32 direct store: 4 lanes x 16 B = 64 B segs
                *(float4*)(Cf + off) = *(float4*)o2[h];
            }
        }
        if (EPI == 4) continue;
        // repack via wave-private scratch -> 64 B segment stores
#pragma unroll
        for (int h = 0; h < 2; h++)
            *(uint2*)&sc[cc * SSTR + h * 16 + q * 4] = pack4(o2[h]);
        uint4 pk = *(const uint4*)&sc[rtok * SSTR + roct];
        *(uint4*)(Cb + (size_t)(t0 + rtok) * 256 + n0 + pr * 32 + roct) = pk;
        if (EPI == 1 || EPI == 5) {  // second output (Zout / Rout)
#pragma unroll
            for (int h = 0; h < 2; h++)
                *(uint2*)&sc[cc * SSTR + h * 16 + q * 4] = pack4(z2[h]);
            uint4 pk2 = *(const uint4*)&sc[rtok * SSTR + roct];
            unsigned short* P2 = (EPI == 1) ? Zout : Rout;
            *(uint4*)(P2 + (size_t)(t0 + rtok) * 256 + n0 + pr * 32 + roct) = pk2;
        }
    }
}

// ---------------------------------------------------------------------------
// Reduction GEMM with transpose-on-load (unchanged from R7).
// ---------------------------------------------------------------------------
__global__ __launch_bounds__(256, 2) void rgemm_k(
    const unsigned short* __restrict__ Kb, const unsigned short* __restrict__ h1b,
    const unsigned short* __restrict__ dz0b,
    const unsigned short* __restrict__ dz1b, float* __restrict__ pbuf) {
    __shared__ unsigned short As[128 * 40];
    __shared__ unsigned short Bs2[128 * 40];
    const int z = blockIdx.z, layer = z >> 6, zc = z & 63;
    const unsigned short* Ag = layer ? h1b : Kb;
    const unsigned short* Bg = layer ? dz1b : dz0b;
    const int t0 = zc * 512;
    const int j0 = blockIdx.x * 128, i0 = blockIdx.y * 128;
    const int tid = threadIdx.x, lane = tid & 63, wave = tid >> 6;
    const int wr = (wave >> 1) * 64, wc = (wave & 1) * 64;
    const int fr = lane & 15, fk = (lane >> 4) * 8;
    const int pt = (tid >> 4) * 2, pi = (tid & 15) * 8;

    f32x4 acc[4][4];
#pragma unroll
    for (int i = 0; i < 4; i++)
#pragma unroll
        for (int j = 0; j < 4; j++) acc[i][j] = (f32x4){0.f, 0.f, 0.f, 0.f};

    for (int tt = t0; tt < t0 + 512; tt += 32) {
        uint4 a0 = *(const uint4*)(Ag + (size_t)(tt + pt) * 256 + i0 + pi);
        uint4 a1 = *(const uint4*)(Ag + (size_t)(tt + pt + 1) * 256 + i0 + pi);
        uint4 b0 = *(const uint4*)(Bg + (size_t)(tt + pt) * 256 + j0 + pi);
        uint4 b1 = *(const uint4*)(Bg + (size_t)(tt + pt + 1) * 256 + j0 + pi);
        const unsigned int* aw0 = (const unsigned int*)&a0;
        const unsigned int* aw1 = (const unsigned int*)&a1;
        const unsigned int* bw0 = (const unsigned int*)&b0;
        const unsigned int* bw1 = (const unsigned int*)&b1;
#pragma unroll
        for (int ii = 0; ii < 8; ii++) {
            unsigned int alo = (aw0[ii >> 1] >> (16 * (ii & 1))) & 0xFFFFu;
            unsigned int ahi = (aw1[ii >> 1] >> (16 * (ii & 1))) & 0xFFFFu;
            unsigned int blo = (bw0[ii >> 1] >> (16 * (ii & 1))) & 0xFFFFu;
            unsigned int bhi = (bw1[ii >> 1] >> (16 * (ii & 1))) & 0xFFFFu;
            const int ad = ((pi + ii) * 40 + pt) >> 1;
            ((unsigned int*)As)[ad] = alo | (ahi << 16);
            ((unsigned int*)Bs2)[ad] = blo | (bhi << 16);
        }
        __syncthreads();
        bf16x8 af[4], bfr[4];
#pragma unroll
        for (int i = 0; i < 4; i++) {
            af[i] = *(const bf16x8*)&As[(wr + i * 16 + fr) * 40 + fk];
            bfr[i] = *(const bf16x8*)&Bs2[(wc + i * 16 + fr) * 40 + fk];
        }
#pragma unroll
        for (int i = 0; i < 4; i++)
#pragma unroll
            for (int j = 0; j < 4; j++)
                acc[i][j] = __builtin_amdgcn_mfma_f32_16x16x32_bf16(
                    af[i], bfr[j], acc[i][j], 0, 0, 0);
        __syncthreads();
    }

    float* P = pbuf + (size_t)((layer << 6) + zc) * 65536;
    const int r0 = (lane >> 4) * 4, cc = lane & 15;
#pragma unroll
    for (int mi = 0; mi < 4; mi++)
#pragma unroll
        for (int ni = 0; ni < 4; ni++) {
            f32x4 c = acc[mi][ni];
#pragma unroll
            for (int r = 0; r < 4; r++)
                P[(size_t)(i0 + wr + mi * 16 + r0 + r) * 256 +
                  (j0 + wc + ni * 16 + cc)] = c[r];
        }
}

__global__ void reduce_k(const float* __restrict__ pbuf, float* __restrict__ accW) {
    int idx = blockIdx.x * 256 + threadIdx.x;  // 131072
    int layer = idx >> 16, rc = idx & 65535;
    const float* p = pbuf + (size_t)layer * 64 * 65536 + rc;
    float s = 0.f;
#pragma unroll 8
    for (int c = 0; c < 64; c++) s += p[(size_t)c * 65536];
    accW[idx] = s;
}

// column sums of a bf16 [32768,256] matrix -> gb[256]
__global__ __launch_bounds__(256) void colsum_k(const unsigned short* __restrict__ dz,
                                                float* __restrict__ gb) {
    const int col = threadIdx.x;
    const size_t r0 = (size_t)blockIdx.x * 128;
    float s0 = 0, s1 = 0, s2 = 0, s3 = 0;
    for (int r = 0; r < 128; r += 4) {
        s0 += b2f(dz[(r0 + r) * 256 + col]);
        s1 += b2f(dz[(r0 + r + 1) * 256 + col]);
        s2 += b2f(dz[(r0 + r + 2) * 256 + col]);
        s3 += b2f(dz[(r0 + r + 3) * 256 + col]);
    }
    atomicAdd(&gb[col], s0 + s1 + s2 + s3);
}

// x fp32 -> xb bf16 + alr = 0.1*sigmoid(x@Wlr+blr), one wave per row
__global__ __launch_bounds__(256) void prep_k(const float* __restrict__ x,
                                              const float* __restrict__ Wlr,
                                              const float* __restrict__ blr,
                                              unsigned short* __restrict__ xb,
                                              float* __restrict__ alr) {
    const int wave = threadIdx.x >> 6, lane = threadIdx.x & 63;
    const int r = blockIdx.x * 4 + wave;
    float4 w = *(const float4*)(Wlr + lane * 4);
    float4 v = *(const float4*)(x + (size_t)r * 256 + lane * 4);
    float s = v.x * w.x + v.y * w.y + v.z * w.z + v.w * w.w;
    unsigned int p0 = (unsigned int)f2b(v.x) | ((unsigned int)f2b(v.y) << 16);
    unsigned int p1 = (unsigned int)f2b(v.z) | ((unsigned int)f2b(v.w) << 16);
    *(uint2*)(xb + (size_t)r * 256 + lane * 4) = make_uint2(p0, p1);
#pragma unroll
    for (int off = 32; off; off >>= 1) s += __shfl_down(s, off);
    if (lane == 0) alr[r] = 0.1f * sigm(s + blr[0]);
}

// weight prep: z=0..4 transpose+cvt {Wk,Wq,Wv,Ws0,Ws1}; z=5 straight cvt Ws1
__global__ void wprep_k(const float* __restrict__ Wk, const float* __restrict__ Wq,
                        const float* __restrict__ Wv, const float* __restrict__ Ws,
                        unsigned short* __restrict__ wt) {
    const int z = blockIdx.y;
    const int idx = blockIdx.x * 256 + threadIdx.x;  // 0..65535
    const float* src = z == 0 ? Wk : z == 1 ? Wq : z == 2 ? Wv
                     : z == 3 ? Ws : Ws + 65536;
    unsigned short* dst = wt + (size_t)z * 65536;
    float v = src[idx];
    if (z == 5)
        dst[idx] = f2b(v);
    else
        dst[(idx & 255) * 256 + (idx >> 8)] = f2b(v);
}

__global__ void adamw_w_k(const float* __restrict__ Ws,
                          const float* __restrict__ accW,
                          unsigned short* __restrict__ nWt,
                          float* __restrict__ outSW) {
    int idx = blockIdx.x * 256 + threadIdx.x;  // 131072
    float g = accW[idx];
    outSW[idx] = -g;
    float nw = Ws[idx] * (1.f - LRc * WDc) - LRc * g / (fabsf(g) + EPSc);
    int l = idx >> 16, k = (idx >> 8) & 255, n = idx & 255;
    nWt[(size_t)l * 65536 + n * 256 + k] = f2b(nw);
}

__global__ void adamw_b_k(const float* __restrict__ bs,
                          const float* __restrict__ accB,
                          float* __restrict__ nb, float* __restrict__ outSb) {
    int idx = blockIdx.x * 256 + threadIdx.x;  // 512
    float g = accB[idx];
    outSb[idx] = -g;
    nb[idx] = bs[idx] * (1.f - LRc * WDc) - LRc * g / (fabsf(g) + EPSc);
}

__global__ void zero_k(float* p, int n) {
    int i = blockIdx.x * 256 + threadIdx.x;
    if (i < n) p[i] = 0.f;
}

extern "C" void kernel_launch(void* const* d_in, const int* in_sizes, int n_in,
                              void* d_out, int out_size, void* d_ws,
                              size_t ws_size, hipStream_t stream) {
    const float* x = (const float*)d_in[0];
    const float* Wk = (const float*)d_in[1];
    const float* Wq = (const float*)d_in[2];
    const float* Wv = (const float*)d_in[3];
    const float* Wlr = (const float*)d_in[4];
    const float* blr = (const float*)d_in[5];
    const float* Ws = (const float*)d_in[6];
    const float* bs = (const float*)d_in[7];

    unsigned short* S = (unsigned short*)d_ws;
    unsigned short* xb = S + 0 * NM;  // dead after proj; reused as r1b
    unsigned short* Kb = S + 1 * NM;
    unsigned short* Qb = S + 2 * NM;
    unsigned short* Vb = S + 3 * NM;
    unsigned short* z0b = S + 4 * NM;
    unsigned short* h1b = S + 5 * NM;
    unsigned short* dz1b = S + 6 * NM;
    unsigned short* dh2b = S + 7 * NM;
    unsigned short* dz0b = S + 8 * NM;
    float* pbuf = (float*)(S + 9 * NM);  // 32 MB (slots 9-10)
    unsigned short* r1b = xb;

    unsigned short* wt = S + 11 * NM;
    unsigned short* W0t = wt + 3 * 65536;
    unsigned short* W1t = wt + 4 * 65536;
    unsigned short* W1b = wt + 5 * 65536;
    unsigned short* nW0t = wt + 6 * 65536;
    unsigned short* nW1t = wt + 7 * 65536;
    float* ft = (float*)(wt + 8 * 65536);
    float* alr = ft;              // 32768
    float* accW = ft + 32768;     // 131072
    float* accB = accW + 131072;  // 512
    float* nb = accB + 512;       // 512

    float* out_ret = (float*)d_out;
    float* out_sW = out_ret + NM;
    float* out_sb = out_sW + 131072;

    dim3 blk5(512);
    dim3 blk(256);
    dim3 g_tall(2, 256);

    zero_k<<<2, blk, 0, stream>>>(accB, 512);
    prep_k<<<8192, blk, 0, stream>>>(x, Wlr, blr, xb, alr);
    wprep_k<<<dim3(256, 6), blk, 0, stream>>>(Wk, Wq, Wv, Ws, wt);

    // projections K,Q,V (batched over z)
    wgemm_k<0><<<dim3(2, 256, 3), blk5, 0, stream>>>(
        xb, wt, nullptr, nullptr, nullptr, nullptr, nullptr, Kb, nullptr,
        nullptr, nullptr, NM);

    // fwd layer 0: h1 = K + silu(K@W0 + b0); saves z0
    wgemm_k<1><<<g_tall, blk5, 0, stream>>>(Kb, W0t, bs, nullptr, nullptr,
                                            nullptr, nullptr, h1b, nullptr,
                                            z0b, nullptr, 0);

    // fwd layer 1 + bwd elementwise: dz1, dh2
    wgemm_k<5><<<g_tall, blk5, 0, stream>>>(h1b, W1t, bs + 256, nullptr,
                                            nullptr, Vb, alr, dz1b, nullptr,
                                            nullptr, dh2b, 0);
    colsum_k<<<256, blk, 0, stream>>>(dz1b, accB + 256);

    // bwd layer 0: dz0 = (dz1@W1^T + dh2) * dsilu(z0)
    wgemm_k<2><<<g_tall, blk5, 0, stream>>>(dz1b, W1b, nullptr, dh2b, z0b,
                                            nullptr, nullptr, dz0b, nullptr,
                                            nullptr, nullptr, 0);
    colsum_k<<<256, blk, 0, stream>>>(dz0b, accB);

    // weight grads: transpose-on-load split-K partials + reduce
    rgemm_k<<<dim3(2, 2, 128), blk, 0, stream>>>(Kb, h1b, dz0b, dz1b, pbuf);
    reduce_k<<<512, blk, 0, stream>>>(pbuf, accW);

    // AdamW + surprises
    adamw_w_k<<<512, blk, 0, stream>>>(Ws, accW, nW0t, out_sW);
    adamw_b_k<<<2, blk, 0, stream>>>(bs, accB, nb, out_sb);

    // retrieved with new weights (two tall passes)
    wgemm_k<3><<<g_tall, blk5, 0, stream>>>(Qb, nW0t, nb, nullptr, nullptr,
                                            nullptr, nullptr, r1b, nullptr,
                                            nullptr, nullptr, 0);
    wgemm_k<4><<<g_tall, blk5, 0, stream>>>(r1b, nW1t, nb + 256, nullptr,
                                            nullptr, nullptr, nullptr, nullptr,
                                            out_ret, nullptr, nullptr, 0);
}